// Round 10
// baseline (10948.783 us; speedup 1.0000x reference)
//
#include <hip/hip_runtime.h>

typedef unsigned short u16;
typedef unsigned int u32;
typedef unsigned long long u64;
typedef __attribute__((ext_vector_type(8))) short bf16x8;   // 8 bf16 (4 VGPRs)
typedef __attribute__((ext_vector_type(4))) float f32x4;

#define T_STEPS 1024
#define E_SZ 128
#define U_SZ 256

#define NG 16    // batch groups (16 batches each)
#define MB 16    // batch rows per group
#define NSL 8    // slices per layer (8 L0-wgs + 8 L1-wgs per group)
#define RD 8     // h0 ring depth
#define HS 264   // padded LDS row stride, K=256
#define EPAD 136 // padded LDS row stride, K=128

#define MKTAG(ep, t) (((u32)((ep) & 63) << 10) | (u32)((t) & 1023))

// ---- LDS layout (role-dependent), bytes ----
#define L0_W0T 0
#define L0_R0T 34816
#define L0_X   102400
#define L0_G   106752
#define L0_STG 115456      // tagged u32 staging: 2048 B
#define L0_B   117504
#define L1_W1T 0
#define L1_R1T 67584
#define L1_EPI 135168
#define L1_G   143616
#define L1_STG 152320      // 2048 B
#define L1_B   154368
#define SMEM_TOTAL 154880

// ---- exchange state: TAGGED u32 words (2 KB per slice block = 256 u64) ----
// No flags: each word = (bf16<<16) | MKTAG(epoch, t). Producer: relaxed u64
// stores only (no fence). Consumer: batch load + tag check + retry.
__device__ u64 g_exH0[RD * NG * NSL * 256];  // 2 MiB: h0 ring
__device__ u64 g_exH1[2 * NG * NSL * 256];   // 512 KiB: h1 parity ring
__device__ int g_pr[NG * NSL * 16];          // L1 consume progress (ring guard)
__device__ int g_epoch;                      // bumped by probe each call
__device__ int g_isF32;

__device__ __forceinline__ float bf2f(u16 u) {
  union { u32 i; float f; } v; v.i = ((u32)u) << 16; return v.f;
}
__device__ __forceinline__ u16 f2bf(float f) {
  union { u32 i; float f; } v; v.f = f;
  u32 r = v.i + 0x7fffu + ((v.i >> 16) & 1u);
  return (u16)(r >> 16);
}
__device__ __forceinline__ float sig_(float x) { return 1.f / (1.f + __expf(-x)); }
__device__ __forceinline__ float tnh_(float x) { return 2.f / (1.f + __expf(-2.f * x)) - 1.f; }

// ---- dtype probe: bumps epoch, zeroes ring-guard flags ----
extern "C" __global__ void dtype_probe(const void* W0v) {
  __shared__ int cntBig;
  if (threadIdx.x == 0) cntBig = 0;
  __syncthreads();
  const u16* u = (const u16*)W0v;
  int big = 0;
  for (int i = threadIdx.x; i < 4096; i += 256)
    if ((u[i] & 0x7F80u) >= 0x4100u) big++;
  atomicAdd(&cntBig, big);
  __syncthreads();
  for (int i = threadIdx.x; i < NG * NSL * 16; i += 256) g_pr[i] = 0;
  if (threadIdx.x == 0) {
    g_isF32 = (cntBig > 100) ? 1 : 0;
    g_epoch = g_epoch + 1;     // fresh epoch invalidates all stale tagged data
  }
}

// ---- unpack 4 tagged u64 -> bf16x8 A-fragment ----
__device__ __forceinline__ bf16x8 unpack4(const u64 r[4]) {
  union { u32 w[4]; bf16x8 v; } o;
#pragma unroll
  for (int k = 0; k < 4; k++)
    o.w[k] = ((u32)(r[k] >> 16) & 0xffffu) | ((u32)(r[k] >> 32) & 0xffff0000u);
  return o.v;
}

// ---- poll+load 8 slice blocks' fragments until all tags match ----
__device__ __forceinline__ void pollLoad8(const u64* __restrict__ exch, u64 slot0,
                                          int off, u32 tag, u64 raw[NSL][4]) {
  int it = 0;
  while (true) {
    u32 bad = 0;
#pragma unroll
    for (int j = 0; j < NSL; j++) {
      const u64* p = exch + (slot0 + j) * 256 + off;
#pragma unroll
      for (int k = 0; k < 4; k++) {
        u64 r = __hip_atomic_load(p + k, __ATOMIC_RELAXED, __HIP_MEMORY_SCOPE_AGENT);
        raw[j][k] = r;
        bad |= (((u32)r ^ tag) & 0xffffu) | (((u32)(r >> 32) ^ tag) & 0xffffu);
      }
    }
    if (__all(bad == 0)) break;
    if (++it > 150000) break;            // deadlock -> wrong answer, not hang
    if (it > 64) __builtin_amdgcn_s_sleep(1);
  }
  __atomic_signal_fence(__ATOMIC_ACQUIRE);
}

// ---- post one 2KB tagged block (wave 0): relaxed stores, NO fence/flag ----
__device__ __forceinline__ void postBlkT(u64* __restrict__ exch, u64 blk,
                                         int tid, const u32* __restrict__ stg32) {
  if (tid < 64) {
    const u64* sp = (const u64*)stg32;
    u64* dst = exch + blk * 256 + (tid << 2);
#pragma unroll
    for (int k = 0; k < 4; k++)
      __hip_atomic_store(dst + k, sp[(tid << 2) + k],
                         __ATOMIC_RELAXED, __HIP_MEMORY_SCOPE_AGENT);
  }
}

// ---- ring-guard poll returning min observed progress (amortized) ----
__device__ __forceinline__ int wavePollMin(const int* fA, int tgt, int lane) {
  const int* p = (lane < 8) ? fA + lane * 16 : nullptr;
  int ok = (p == nullptr);
  int v = 0x7fffffff;
  int it = 0;
  while (!__all(ok)) {
    if (!ok) {
      v = __hip_atomic_load(p, __ATOMIC_RELAXED, __HIP_MEMORY_SCOPE_AGENT);
      ok = v >= tgt;
    }
    if (++it > 48) __builtin_amdgcn_s_sleep(1);
    if (it > 500000) break;
  }
  __atomic_signal_fence(__ATOMIC_ACQUIRE);
  int m = (lane < 8) ? v : 0x7fffffff;
#pragma unroll
  for (int off = 4; off; off >>= 1) {
    int o = __shfl_down(m, off);
    m = m < o ? m : o;
  }
  return __shfl(m, 0);
}

extern "C" __global__ void __launch_bounds__(256, 1)
lstm_fused(const int* __restrict__ tokens, const void* __restrict__ emb,
           const void* __restrict__ W0, const void* __restrict__ R0, const void* __restrict__ b0,
           const void* __restrict__ W1, const void* __restrict__ R1, const void* __restrict__ b1,
           const void* __restrict__ Wout, const void* __restrict__ bout,
           void* __restrict__ outv) {
  extern __shared__ char smem[];

  const int tid = threadIdx.x;
  const int b = blockIdx.x;
  const int g = b & (NG - 1);
  const int w = b >> 4;
  const int role = w >> 3;             // 0 = layer-0 wg, 1 = layer-1 wg
  const int sl = w & 7;
  const int isF32 = g_isF32;
  const int ep = g_epoch;

  auto ldf = [&](const void* p, int idx) -> float {
    return isF32 ? ((const float*)p)[idx] : bf2f(((const u16*)p)[idx]);
  };

  const int lane = tid & 63;
  const int wv = tid >> 6;            // wave = gate q (output tiles 2wv, 2wv+1)
  const int ml = lane & 15;
  const int quad = lane >> 4;
  const int um = tid >> 4;
  const int un = tid & 15;
  const int fragOff = (ml << 4) + (quad << 2);   // u64 offset of my A-frag in a block

  int* flp = g_pr + (g << 3) * 16;

  if (role == 0) {
    // ================= LAYER-0 WORKGROUP =================
    u16* w0t = (u16*)(smem + L0_W0T);
    u16* r0t = (u16*)(smem + L0_R0T);
    u16* ldsX = (u16*)(smem + L0_X);
    float* ldsG = (float*)(smem + L0_G);
    u32* stg32 = (u32*)(smem + L0_STG);
    float* ldsB = (float*)(smem + L0_B);

    for (int i = tid; i < 128 * 128; i += 256) {
      int k = i >> 7, n = i & 127;
      int col = ((n >> 5) << 8) + (sl << 5) + (n & 31);
      w0t[n * EPAD + k] = f2bf(ldf(W0, k * 1024 + col));
    }
    for (int i = tid; i < 128 * 256; i += 256) {
      int k = i >> 7, n = i & 127;
      int col = ((n >> 5) << 8) + (sl << 5) + (n & 31);
      r0t[n * HS + k] = f2bf(ldf(R0, k * 1024 + col));
    }
    if (tid < 128) {
      int col = ((tid >> 5) << 8) + (sl << 5) + (tid & 31);
      ldsB[tid] = ldf(b0, col);
    }

    float cst[2] = {0.f, 0.f};
    const int tokBase = (g * MB + um) * T_STEPS;
    int prMin = 0;

    float4 xfA, xfB; uint4 xbf;
    {
      int tok = tokens[tokBase];
      if (isF32) {
        const float* row = (const float*)emb + (u64)tok * E_SZ + (un << 3);
        xfA = *(const float4*)row; xfB = *(const float4*)(row + 4);
      } else {
        xbf = *(const uint4*)((const u16*)emb + (u64)tok * E_SZ + (un << 3));
      }
    }
    __syncthreads();

    const int row0 = (wv << 5) + ml;
    const u16* brA0 = w0t + row0 * EPAD + (quad << 3);
    const u16* brB0 = brA0 + (EPAD << 4);
    const u16* brA2 = r0t + row0 * HS + (quad << 3);
    const u16* brB2 = brA2 + (HS << 4);

    for (int t = 0; t < T_STEPS; t++) {
      // commit x_t
      {
        uint4 pk;
        if (isF32) {
          pk.x = (u32)f2bf(xfA.x) | ((u32)f2bf(xfA.y) << 16);
          pk.y = (u32)f2bf(xfA.z) | ((u32)f2bf(xfA.w) << 16);
          pk.z = (u32)f2bf(xfB.x) | ((u32)f2bf(xfB.y) << 16);
          pk.w = (u32)f2bf(xfB.z) | ((u32)f2bf(xfB.w) << 16);
        } else pk = xbf;
        *(uint4*)(ldsX + um * EPAD + (un << 3)) = pk;
      }
      __syncthreads();

      float ba = ldsB[row0], bb = ldsB[row0 + 16];
      f32x4 acA = {ba, ba, ba, ba}, acB = {bb, bb, bb, bb};

      // x_t @ W0
      {
        const u16* ar = ldsX + ml * EPAD + (quad << 3);
#pragma unroll
        for (int kc = 0; kc < 4; kc++) {
          bf16x8 av = *(const bf16x8*)(ar + kc * 32);
          acA = __builtin_amdgcn_mfma_f32_16x16x32_bf16(av, *(const bf16x8*)(brA0 + kc * 32), acA, 0, 0, 0);
          acB = __builtin_amdgcn_mfma_f32_16x16x32_bf16(av, *(const bf16x8*)(brB0 + kc * 32), acB, 0, 0, 0);
        }
      }

      // h0_{t-1} @ R0: self-validating tagged poll (no flags)
      if (t > 0) {
        u64 raw[NSL][4];
        const u64 s0 = (u64)((((t - 1) & (RD - 1)) * NG + g) * NSL);
        pollLoad8(g_exH0, s0, fragOff, MKTAG(ep, t - 1), raw);
#pragma unroll
        for (int j = 0; j < NSL; j++) {
          bf16x8 av = unpack4(raw[j]);
          acA = __builtin_amdgcn_mfma_f32_16x16x32_bf16(av, *(const bf16x8*)(brA2 + (j << 5)), acA, 0, 0, 0);
          acB = __builtin_amdgcn_mfma_f32_16x16x32_bf16(av, *(const bf16x8*)(brB2 + (j << 5)), acB, 0, 0, 0);
        }
      }

      // gates
#pragma unroll
      for (int r = 0; r < 4; r++) {
        int m = (quad << 2) + r;
        float gA = (wv == 2) ? tnh_(acA[r]) : sig_(acA[r]);
        float gB = (wv == 2) ? tnh_(acB[r]) : sig_(acB[r]);
        ldsG[row0 * 17 + m] = gA;
        ldsG[(row0 + 16) * 17 + m] = gB;
      }
      __syncthreads();

      // cell update -> tagged staging words
      const u32 tagT = MKTAG(ep, t);
#pragma unroll
      for (int j = 0; j < 2; j++) {
        int idx = tid + (j << 8);
        int m = idx >> 5, uu = idx & 31;
        float iv = ldsG[uu * 17 + m];
        float fv = ldsG[(32 + uu) * 17 + m];
        float gv = ldsG[(64 + uu) * 17 + m];
        float ov = ldsG[(96 + uu) * 17 + m];
        float c = fv * cst[j] + iv * gv; cst[j] = c;
        stg32[(m << 5) + uu] = ((u32)f2bf(ov * tnh_(c)) << 16) | tagT;
      }
      __syncthreads();

      // ring guard, amortized
      if (t >= RD && prMin < t - RD + 1)
        prMin = wavePollMin(flp, t - RD + 1, lane);

      // post h0_t (relaxed tagged stores; no fence, no flag)
      postBlkT(g_exH0, (u64)(((t & (RD - 1)) * NG + g) * NSL + sl), tid, stg32);

      // x_{t+1} prefetch
      if (t + 1 < T_STEPS) {
        int tok = tokens[tokBase + t + 1];
        if (isF32) {
          const float* row = (const float*)emb + (u64)tok * E_SZ + (un << 3);
          xfA = *(const float4*)row; xfB = *(const float4*)(row + 4);
        } else {
          xbf = *(const uint4*)((const u16*)emb + (u64)tok * E_SZ + (un << 3));
        }
      }
    }
  } else {
    // ================= LAYER-1 WORKGROUP =================
    u16* w1t = (u16*)(smem + L1_W1T);
    u16* r1t = (u16*)(smem + L1_R1T);
    u16* ldsEpi = (u16*)(smem + L1_EPI);
    float* ldsG = (float*)(smem + L1_G);
    u32* stg32 = (u32*)(smem + L1_STG);
    float* ldsB = (float*)(smem + L1_B);

    for (int i = tid; i < 128 * 256; i += 256) {
      int k = i >> 7, n = i & 127;
      int col = ((n >> 5) << 8) + (sl << 5) + (n & 31);
      w1t[n * HS + k] = f2bf(ldf(W1, k * 1024 + col));
      r1t[n * HS + k] = f2bf(ldf(R1, k * 1024 + col));
    }
    if (tid < 128) {
      int col = ((tid >> 5) << 8) + (sl << 5) + (tid & 31);
      ldsB[tid] = ldf(b1, col);
    }
    __syncthreads();

    float cst[2] = {0.f, 0.f};
    const int row0 = (wv << 5) + ml;
    const u16* brA1 = w1t + row0 * HS + (quad << 3);
    const u16* brB1 = brA1 + (HS << 4);
    const u16* brA2 = r1t + row0 * HS + (quad << 3);
    const u16* brB2 = brA2 + (HS << 4);

    for (int t = 0; t < T_STEPS; t++) {
      float ba = ldsB[row0], bb = ldsB[row0 + 16];
      f32x4 acA = {ba, ba, ba, ba}, acB = {bb, bb, bb, bb};

      // combined tagged poll: h0_t (8 blocks) + h1_{t-1} (8 blocks), one batch
      u64 raw0[NSL][4], raw1[NSL][4];
      {
        const u64 s0 = (u64)(((t & (RD - 1)) * NG + g) * NSL);
        const u64 s1 = (u64)((((t - 1) & 1) * NG + g) * NSL);
        const u32 tag0 = MKTAG(ep, t), tag1 = MKTAG(ep, t - 1);
        const int haveH1 = (t > 0);
        int it = 0;
        while (true) {
          u32 bad = 0;
#pragma unroll
          for (int j = 0; j < NSL; j++) {
            const u64* p = g_exH0 + (s0 + j) * 256 + fragOff;
#pragma unroll
            for (int k = 0; k < 4; k++) {
              u64 r = __hip_atomic_load(p + k, __ATOMIC_RELAXED, __HIP_MEMORY_SCOPE_AGENT);
              raw0[j][k] = r;
              bad |= (((u32)r ^ tag0) & 0xffffu) | (((u32)(r >> 32) ^ tag0) & 0xffffu);
            }
          }
          if (haveH1) {
#pragma unroll
            for (int j = 0; j < NSL; j++) {
              const u64* p = g_exH1 + (s1 + j) * 256 + fragOff;
#pragma unroll
              for (int k = 0; k < 4; k++) {
                u64 r = __hip_atomic_load(p + k, __ATOMIC_RELAXED, __HIP_MEMORY_SCOPE_AGENT);
                raw1[j][k] = r;
                bad |= (((u32)r ^ tag1) & 0xffffu) | (((u32)(r >> 32) ^ tag1) & 0xffffu);
              }
            }
          }
          if (__all(bad == 0)) break;
          if (++it > 150000) break;
          if (it > 64) __builtin_amdgcn_s_sleep(1);
        }
        __atomic_signal_fence(__ATOMIC_ACQUIRE);
      }

      // h0_t @ W1
#pragma unroll
      for (int j = 0; j < NSL; j++) {
        bf16x8 av = unpack4(raw0[j]);
        acA = __builtin_amdgcn_mfma_f32_16x16x32_bf16(av, *(const bf16x8*)(brA1 + (j << 5)), acA, 0, 0, 0);
        acB = __builtin_amdgcn_mfma_f32_16x16x32_bf16(av, *(const bf16x8*)(brB1 + (j << 5)), acB, 0, 0, 0);
      }
      // h1_{t-1} @ R1
      if (t > 0) {
#pragma unroll
        for (int j = 0; j < NSL; j++) {
          bf16x8 av = unpack4(raw1[j]);
          acA = __builtin_amdgcn_mfma_f32_16x16x32_bf16(av, *(const bf16x8*)(brA2 + (j << 5)), acA, 0, 0, 0);
          acB = __builtin_amdgcn_mfma_f32_16x16x32_bf16(av, *(const bf16x8*)(brB2 + (j << 5)), acB, 0, 0, 0);
        }
      }

      // gates
#pragma unroll
      for (int r = 0; r < 4; r++) {
        int m = (quad << 2) + r;
        float gA = (wv == 2) ? tnh_(acA[r]) : sig_(acA[r]);
        float gB = (wv == 2) ? tnh_(acB[r]) : sig_(acB[r]);
        ldsG[row0 * 17 + m] = gA;
        ldsG[(row0 + 16) * 17 + m] = gB;
      }
      __syncthreads();

      // ring-slot release (all 4 waves consumed h0 before the barrier)
      if (tid == 0) {
        __atomic_signal_fence(__ATOMIC_RELEASE);
        __hip_atomic_store(g_pr + ((g << 3) + sl) * 16, t + 1,
                           __ATOMIC_RELAXED, __HIP_MEMORY_SCOPE_AGENT);
      }

      // cell update -> tagged staging
      const u32 tagT = MKTAG(ep, t);
#pragma unroll
      for (int j = 0; j < 2; j++) {
        int idx = tid + (j << 8);
        int m = idx >> 5, uu = idx & 31;
        float iv = ldsG[uu * 17 + m];
        float fv = ldsG[(32 + uu) * 17 + m];
        float gv = ldsG[(64 + uu) * 17 + m];
        float ov = ldsG[(96 + uu) * 17 + m];
        float c = fv * cst[j] + iv * gv; cst[j] = c;
        stg32[(m << 5) + uu] = ((u32)f2bf(ov * tnh_(c)) << 16) | tagT;
      }
      __syncthreads();

      // post h1_t (relaxed tagged stores)
      postBlkT(g_exH1, (u64)(((t & 1) * NG + g) * NSL + sl), tid, stg32);
    }

    // ---- epilogue: tagged read of h1_{T-1}, then logits ----
    if (sl == 0) {
      const u64 s1 = (u64)((((T_STEPS - 1) & 1) * NG + g) * NSL);
      const u32 tagE = MKTAG(ep, T_STEPS - 1);
      const int sp = tid >> 5, q2 = tid & 31;
      const u64* p = g_exH1 + (s1 + sp) * 256 + q2 * 8;
      u64 r[8];
      int it = 0;
      while (true) {
        u32 bad = 0;
#pragma unroll
        for (int k = 0; k < 8; k++) {
          r[k] = __hip_atomic_load(p + k, __ATOMIC_RELAXED, __HIP_MEMORY_SCOPE_AGENT);
          bad |= (((u32)r[k] ^ tagE) & 0xffffu) | (((u32)(r[k] >> 32) ^ tagE) & 0xffffu);
        }
        if (bad == 0) break;
        if (++it > 300000) break;
        if (it > 32) __builtin_amdgcn_s_sleep(2);
      }
#pragma unroll
      for (int k = 0; k < 8; k++) {
        int widx = q2 * 16 + 2 * k;          // word index in block
        int m = widx >> 5, uu = widx & 31;
        ldsEpi[m * HS + (sp << 5) + uu] = (u16)(r[k] >> 16);
        ldsEpi[m * HS + (sp << 5) + uu + 1] = (u16)(r[k] >> 48);
      }
      __syncthreads();
      float* woutf = ldsG;
      float* red = ldsG + 272;
      woutf[tid] = ldf(Wout, tid);
      __syncthreads();
      float pacc = 0.f;
#pragma unroll
      for (int j = 0; j < 16; j++)
        pacc += bf2f(ldsEpi[um * HS + (un << 4) + j]) * woutf[(un << 4) + j];
      red[um * 17 + un] = pacc;
      __syncthreads();
      if (tid < 16) {
        float sum = ldf(bout, 0);
#pragma unroll
        for (int j = 0; j < 16; j++) sum += red[tid * 17 + j];
        float val = sig_(sum);
        if (isF32) ((float*)outv)[g * MB + tid] = val;
        else       ((u16*)outv)[g * MB + tid] = f2bf(val);
      }
    }
  }
}

extern "C" void kernel_launch(void* const* d_in, const int* in_sizes, int n_in,
                              void* d_out, int out_size, void* d_ws, size_t ws_size,
                              hipStream_t stream) {
  const int* tokens = (const int*)d_in[0];
  const void* emb  = d_in[1];
  const void* W0   = d_in[2];
  const void* R0   = d_in[3];
  const void* b0   = d_in[4];
  const void* W1   = d_in[5];
  const void* R1   = d_in[6];
  const void* b1   = d_in[7];
  const void* Wout = d_in[8];
  const void* bout = d_in[9];

  hipFuncSetAttribute((const void*)lstm_fused,
                      hipFuncAttributeMaxDynamicSharedMemorySize, SMEM_TOTAL);

  dtype_probe<<<dim3(1), dim3(256), 0, stream>>>(W0);

  // 256 wgs (16 groups x (8 L0 + 8 L1)), 1 wg/CU: co-resident.
  lstm_fused<<<dim3(256), dim3(256), SMEM_TOTAL, stream>>>(
      tokens, emb, W0, R0, b0, W1, R1, b1, Wout, bout, d_out);
}